// Round 17
// baseline (18810.330 us; speedup 1.0000x reference)
//
#include <hip/hip_runtime.h>
#include <hip/hip_bf16.h>
#include <stdint.h>

#define BB 512
#define NN 200
#define TT 200
#define MM 20
#define H1N 128
#define MEN 32
#define DIN 128
#define H2N 256
#define JDN 256
#define AHN 256

#define PRE_REG 20   // pre rows per wave held in registers (4 waves/batch -> 80 rows)
#define PRE_LDSB 32  // pre rows per batch held in LDS
// per batch: rows [0,80) regs, [80,112) LDS, [112,200) streamed from L3

typedef float f4v __attribute__((ext_vector_type(4)));

// ---------------- threefry2x32 (JAX-exact) ----------------
__device__ __forceinline__ void tf2x32(uint32_t k0, uint32_t k1,
                                       uint32_t x0, uint32_t x1,
                                       uint32_t& o0, uint32_t& o1) {
  uint32_t ks2 = k0 ^ k1 ^ 0x1BD11BDAu;
  x0 += k0; x1 += k1;
#define TF_RND(R) { x0 += x1; x1 = (x1 << (R)) | (x1 >> (32 - (R))); x1 ^= x0; }
  TF_RND(13) TF_RND(15) TF_RND(26) TF_RND(6)   x0 += k1;  x1 += ks2 + 1u;
  TF_RND(17) TF_RND(29) TF_RND(16) TF_RND(24)  x0 += ks2; x1 += k0 + 2u;
  TF_RND(13) TF_RND(15) TF_RND(26) TF_RND(6)   x0 += k0;  x1 += k1 + 3u;
  TF_RND(17) TF_RND(29) TF_RND(16) TF_RND(24)  x0 += k1;  x1 += ks2 + 4u;
  TF_RND(13) TF_RND(15) TF_RND(26) TF_RND(6)   x0 += ks2; x1 += k0 + 5u;
#undef TF_RND
  o0 = x0; o1 = x1;
}

// fast tanh for the scores phase (verified R11-R16, absmax <=0.0625):
// tanh(x) = 1 - 2/(exp(2x)+1) via v_exp_f32 + v_rcp_f32 + 1 Newton step.
__device__ __forceinline__ float ftanh(float x) {
  float e = __builtin_amdgcn_exp2f(x * 2.8853900817779268f);  // exp(2x)
  float d = e + 1.0f;
  float r = __builtin_amdgcn_rcpf(d);
  r = r * (2.0f - d * r);
  return 1.0f - 2.0f * r;
}

// ---------------- small utility kernels ----------------
__global__ void k_transpose(const float* __restrict__ in, float* __restrict__ out,
                            int R, int C) {
  int idx = blockIdx.x * 256 + threadIdx.x;
  if (idx < R * C) { int r = idx / C, c = idx - r * C; out[c * R + r] = in[idx]; }
}

// Wc2[k*256+o]: k<128 -> w2ih[o*128+k]; k>=128 -> w2hh[o*256+(k-128)]
__global__ void k_pack2(const float* __restrict__ w2ih, const float* __restrict__ w2hh,
                        float* __restrict__ Wc2) {
  int idx = blockIdx.x * 256 + threadIdx.x;     // 384*256
  int o = idx & 255, k = idx >> 8;
  Wc2[idx] = (k < 128) ? w2ih[o * 128 + k] : w2hh[o * 256 + (k - 128)];
}

__global__ void k_copy4(const f4v* __restrict__ in, f4v* __restrict__ out, int n4) {
  int i = blockIdx.x * 256 + threadIdx.x;
  if (i < n4) out[i] = in[i];
}

// ---------------- pre_att = enc @ W1^T + b1 ----------------
#define NR 20
__global__ __launch_bounds__(256) void k_pre(const float* __restrict__ enc,
                                             const float* __restrict__ W1T,
                                             const float* __restrict__ ab1,
                                             float* __restrict__ pre) {
  const int b = blockIdx.y, n0 = blockIdx.x * NR, tid = threadIdx.x;
  __shared__ __align__(16) float es[NR * JDN];
  for (int r = 0; r < NR; ++r)
    es[r * JDN + tid] = enc[((size_t)(b * NN + n0 + r)) * JDN + tid];
  __syncthreads();
  float acc[NR];
#pragma unroll
  for (int r = 0; r < NR; ++r) acc[r] = 0.0f;
  const f4v* es4 = (const f4v*)es;
  for (int k0 = 0; k0 < JDN; k0 += 4) {
    float w0 = W1T[(k0 + 0) * AHN + tid];
    float w1 = W1T[(k0 + 1) * AHN + tid];
    float w2 = W1T[(k0 + 2) * AHN + tid];
    float w3 = W1T[(k0 + 3) * AHN + tid];
#pragma unroll
    for (int r = 0; r < NR; ++r) {
      f4v e = es4[r * 64 + (k0 >> 2)];
      acc[r] += e.x * w0 + e.y * w1 + e.z * w2 + e.w * w3;
    }
  }
  float bb = ab1[tid];
  for (int r = 0; r < NR; ++r)
    pre[((size_t)(b * NN + n0 + r)) * AHN + tid] = acc[r] + bb;
}

// ---------------- di table: step1 RNN + fc for all (b, n) ----------------
// chain = b*201 + n; n==200 is the zero-P initial state. (verified round 4)
__global__ __launch_bounds__(512) void k_di(
    const float* __restrict__ pt, const float* __restrict__ nm,
    const float* __restrict__ w1ih, const float* __restrict__ b1,
    const float* __restrict__ whh,
    const float* __restrict__ mw, const float* __restrict__ mb,
    const float* __restrict__ fcWT, const float* __restrict__ fcb,
    float* __restrict__ diOut) {
  const int chain = blockIdx.x;
  const int b = chain / 201, n = chain - b * 201;
  const int tid = threadIdx.x;
  const int w = tid >> 6, l = tid & 63;

  __shared__ __align__(16) float hm[320];
  __shared__ float Ps[40];
  __shared__ float partial[512];

  const int j = (w << 4) + (l & 15);
  const int ks = l >> 4;
  float wr[32];
  {
    const float* wp = whh + j * H1N + ks * 32;
#pragma unroll
    for (int i = 0; i < 32; i += 4) {
      f4v t4 = *(const f4v*)(wp + i);
      wr[i] = t4.x; wr[i + 1] = t4.y; wr[i + 2] = t4.z; wr[i + 3] = t4.w;
    }
  }
  const float w1a = w1ih[2 * j], w1b = w1ih[2 * j + 1], b1j = b1[j];
  const float fcb_r = (tid < 128) ? fcb[tid] : 0.0f;

  if (tid < 32)  hm[288 + tid] = nm[b] * mw[tid] + mb[tid];
  if (tid >= 64 && tid < 192) {
    int p = tid - 64;
    hm[(p >> 5) * 36 + (p & 31)] = 0.0f;
  }
  if (tid < 40)
    Ps[tid] = (n < NN) ? pt[((size_t)(b * NN + n)) * (MM * 2) + tid] : 0.0f;
  __syncthreads();

  for (int m = 0; m < MM; ++m) {
    float x0 = Ps[2 * m], x1 = Ps[2 * m + 1];
    float acc = 0.0f;
    const f4v* hm4 = (const f4v*)(hm + (m & 1) * 144 + ks * 36);
#pragma unroll
    for (int i = 0; i < 8; ++i) {
      f4v hv = hm4[i];
      acc += wr[4 * i] * hv.x;     acc += wr[4 * i + 1] * hv.y;
      acc += wr[4 * i + 2] * hv.z; acc += wr[4 * i + 3] * hv.w;
    }
    acc += __shfl_xor(acc, 16);
    acc += __shfl_xor(acc, 32);
    if (ks == 0) {
      float hv = tanhf(acc + x0 * w1a + x1 * w1b + b1j);
      hm[(1 - (m & 1)) * 144 + (j >> 5) * 36 + (j & 31)] = hv;
    }
    __syncthreads();
  }

  {
    const int ksf = tid >> 7, o = tid & 127, k0 = ksf * 40;
    float a0=0,a1=0,a2=0,a3=0,a4=0,a5=0,a6=0,a7=0;
#pragma unroll
    for (int i0 = 0; i0 < 40; i0 += 8) {
#pragma unroll
      for (int q8 = 0; q8 < 8; ++q8) {
        int k = k0 + i0 + q8;
        float hv = (k < 128) ? hm[(k >> 5) * 36 + (k & 31)] : hm[288 + (k - 128)];
        float wv = fcWT[k * 128 + o];
        if (q8 == 0) a0 += hv * wv; else if (q8 == 1) a1 += hv * wv;
        else if (q8 == 2) a2 += hv * wv; else if (q8 == 3) a3 += hv * wv;
        else if (q8 == 4) a4 += hv * wv; else if (q8 == 5) a5 += hv * wv;
        else if (q8 == 6) a6 += hv * wv; else a7 += hv * wv;
      }
    }
    partial[tid] = ((a0 + a1) + (a2 + a3)) + ((a4 + a5) + (a6 + a7));
    __syncthreads();
    if (tid < 128)
      diOut[(size_t)chain * 128 + tid] =
          partial[tid] + partial[128 + tid] + partial[256 + tid] +
          partial[384 + tid] + fcb_r;
  }
}

// ---------------- k_full: R15 + k-half-split matvec (single change) ----------------
// 256 blocks x 512 threads (1 block/CU). Block = 2 batches. Matvec: thread
// (o=tid&255, hh=tid>>8) covers k-half [hh*16,hh*16+16) of each tile for BOTH
// batches -> each weight b32 read shared across 2 FMAs (reads halve);
// partial[] reduce at the two handoffs. Scores phase: R15 verbatim.
__global__ __launch_bounds__(512) void k_full(
    const float* __restrict__ pre, const float* __restrict__ attv,
    const float* __restrict__ Wc2, const float* __restrict__ b2,
    const float* __restrict__ attW2T, const float* __restrict__ ab2,
    const float* __restrict__ d0h, const float* __restrict__ di,
    float* __restrict__ out_idx, float* __restrict__ out_logp) {
  const int b0 = blockIdx.x * 2, tid = threadIdx.x;
  const int w = tid >> 6, l = tid & 63;
  const int o = tid & 255, hh = tid >> 8;       // matvec role: output o, k-half hh
  const int sg = w >> 2, wg = w & 3;            // sampling role
  const int tid2 = wg * 64 + l;

  __shared__ __align__(16) float wlds[2][8192];        // 2 x 32KB weight tiles
  __shared__ __align__(16) float pre_lds[2][PRE_LDSB * 256];
  __shared__ __align__(16) float xcb[2][2][384];       // [batch][buf][di(128);h2(256)]
  __shared__ __align__(16) float partial[1024];        // [hh][batch][o]
  __shared__ __align__(16) float qs_g[2][256];
  __shared__ float ms[2][200];
  __shared__ float av[2][200];
  __shared__ float wredv[2][4]; __shared__ int wredi[2][4];
  __shared__ float wmaxs[2][4]; __shared__ float wsums[2][4];
  __shared__ int schosen[2]; __shared__ float smaxs[2], ssums[2];

  // ---- pin pre rows 0..79 (regs, per batch via sg) ----
  float preg[PRE_REG][4];
  const float* pb = pre + (size_t)(b0 + sg) * NN * AHN;
#pragma unroll
  for (int r = 0; r < PRE_REG; ++r) {
    const float* pr = pb + (size_t)(wg * PRE_REG + r) * AHN + l;
#pragma unroll
    for (int jj = 0; jj < 4; ++jj) preg[r][jj] = pr[jj * 64];
  }
  // ---- pin pre rows 80..111 in LDS (both batches) ----
  for (int i = tid; i < 2 * PRE_LDSB * 64; i += 512) {
    int bb = i >> 11;                 // 2048 f4v per batch
    int rem = i & 2047;
    ((f4v*)pre_lds[bb])[rem] =
        ((const f4v*)(pre + ((size_t)((b0 + bb) * NN + 80)) * AHN))[rem];
  }

  const float b2r  = b2[o];
  const float ab2r = ab2[o];
  const float v0 = attv[l], v1 = attv[l + 64], v2 = attv[l + 128], v3 = attv[l + 192];

  xcb[hh][0][128 + o] = d0h[o];
  if (tid < 256) {
    int gg = tid >> 7, k = tid & 127;
    float dv = di[((size_t)((b0 + gg) * 201 + 200)) * 128 + k];
    xcb[gg][0][k] = dv; xcb[gg][1][k] = dv;
  }
  if (tid < 400) { int gg = tid / 200, n = tid - gg * 200; av[gg][n] = 1.0f; }

  // ---- prologue: stage tile 0 (first 32KB of Wc2) ----
  {
    const f4v* src = (const f4v*)Wc2;
    f4v* dst = (f4v*)wlds[0];
    dst[tid] = src[tid]; dst[512 + tid] = src[512 + tid];
    dst[1024 + tid] = src[1024 + tid]; dst[1536 + tid] = src[1536 + tid];
  }
  __syncthreads();

  for (int t = 0; t < TT; ++t) {
    const int XB = t & 1, NB = XB ^ 1;
    uint32_t sk0, sk1; tf2x32(0u, 42u, 0u, (uint32_t)t, sk0, sk1);

    float a1A = 0.0f, a1B = 0.0f, a2A = 0.0f, a2B = 0.0f;
    for (int tile = 0; tile < 20; ++tile) {
      const int cur = tile & 1;
      // stage next tile (wraps to next step's tile 0 at tile==19)
      int nt = tile + 1; if (nt == 20) nt = 0;
      const f4v* src = (const f4v*)((nt < 12) ? (Wc2 + nt * 8192)
                                              : (attW2T + (nt - 12) * 8192));
      f4v s0 = src[tid], s1 = src[512 + tid], s2 = src[1024 + tid],
          s3 = src[1536 + tid];

      if (tile == 12) {           // h2n handoff: a1* final after tile 11
        partial[(hh * 2 + 0) * 256 + o] = a1A;
        partial[(hh * 2 + 1) * 256 + o] = a1B;
        __syncthreads();
        // thread (o,hh) produces output o of batch hh: sum both k-halves
        xcb[hh][NB][128 + o] =
            tanhf(partial[(0 * 2 + hh) * 256 + o] +
                  partial[(1 * 2 + hh) * 256 + o] + b2r);
        __syncthreads();
      }

      const int koff = (tile < 12) ? (tile * 32 + hh * 16)
                                   : (128 + (tile - 12) * 32 + hh * 16);
      const int bufsel = (tile < 12) ? XB : NB;
      const f4v* xA4 = (const f4v*)(&xcb[0][bufsel][koff]);
      const f4v* xB4 = (const f4v*)(&xcb[1][bufsel][koff]);
      f4v xa0 = xA4[0], xa1 = xA4[1], xa2 = xA4[2], xa3 = xA4[3];
      f4v xb0 = xB4[0], xb1 = xB4[1], xb2 = xB4[2], xb3 = xB4[3];

      const float* wl = wlds[cur] + (size_t)(hh * 16) * 256 + o;
      float aA = 0.0f, aB = 0.0f;
#pragma unroll
      for (int kk = 0; kk < 16; ++kk) {
        float wv = wl[kk * 256];
        float xav = (kk < 4) ? xa0[kk] : (kk < 8) ? xa1[kk - 4]
                   : (kk < 12) ? xa2[kk - 8] : xa3[kk - 12];
        float xbv = (kk < 4) ? xb0[kk] : (kk < 8) ? xb1[kk - 4]
                   : (kk < 12) ? xb2[kk - 8] : xb3[kk - 12];
        aA += xav * wv;
        aB += xbv * wv;
      }
      if (tile < 12) { a1A += aA; a1B += aB; } else { a2A += aA; a2B += aB; }

      f4v* wd = (f4v*)wlds[cur ^ 1];
      wd[tid] = s0; wd[512 + tid] = s1; wd[1024 + tid] = s2; wd[1536 + tid] = s3;
      __syncthreads();
    }

    partial[(hh * 2 + 0) * 256 + o] = a2A;
    partial[(hh * 2 + 1) * 256 + o] = a2B;
    __syncthreads();
    qs_g[hh][o] = partial[(0 * 2 + hh) * 256 + o] +
                  partial[(1 * 2 + hh) * 256 + o] + ab2r;
    __syncthreads();

    // ---- scores: R15 verbatim (wave wg of batch sg, 50 rows, single-row reduce) ----
    {
      const float q0 = qs_g[sg][l],       q1 = qs_g[sg][l + 64];
      const float q2 = qs_g[sg][l + 128], q3 = qs_g[sg][l + 192];
#pragma unroll
      for (int r = 0; r < PRE_REG; ++r) {
        float s0 = ftanh(preg[r][0] + q0) * v0;
        float s1 = ftanh(preg[r][1] + q1) * v1;
        float s2 = ftanh(preg[r][2] + q2) * v2;
        float s3 = ftanh(preg[r][3] + q3) * v3;
        float s = (s0 + s1) + (s2 + s3);
#pragma unroll
        for (int d = 32; d > 0; d >>= 1) s += __shfl_down(s, d);
        if (l == 0) ms[sg][wg * PRE_REG + r] = s;
      }
#pragma unroll
      for (int i = 0; i < 8; ++i) {
        const float* pr = pre_lds[sg] + (wg * 8 + i) * 256;
        float s0 = ftanh(pr[l]       + q0) * v0;
        float s1 = ftanh(pr[l + 64]  + q1) * v1;
        float s2 = ftanh(pr[l + 128] + q2) * v2;
        float s3 = ftanh(pr[l + 192] + q3) * v3;
        float s = (s0 + s1) + (s2 + s3);
#pragma unroll
        for (int d = 32; d > 0; d >>= 1) s += __shfl_down(s, d);
        if (l == 0) ms[sg][80 + wg * 8 + i] = s;
      }
      // streamed rows 112..199, depth-1 prefetch
      const float* prow = pb + (size_t)(112 + wg * 22) * AHN;
      float c0 = prow[l], c1 = prow[l + 64], c2 = prow[l + 128], c3 = prow[l + 192];
      for (int i = 0; i < 22; ++i) {
        const float* nr = prow + AHN;
        float n0 = 0, n1 = 0, n2 = 0, n3 = 0;
        if (i < 21) { n0 = nr[l]; n1 = nr[l + 64]; n2 = nr[l + 128]; n3 = nr[l + 192]; }
        float s0 = ftanh(c0 + q0) * v0;
        float s1 = ftanh(c1 + q1) * v1;
        float s2 = ftanh(c2 + q2) * v2;
        float s3 = ftanh(c3 + q3) * v3;
        float s = (s0 + s1) + (s2 + s3);
#pragma unroll
        for (int d = 32; d > 0; d >>= 1) s += __shfl_down(s, d);
        if (l == 0) ms[sg][112 + wg * 22 + i] = s;
        c0 = n0; c1 = n1; c2 = n2; c3 = n3; prow = nr;
      }
    }
    __syncthreads();

    // ---- gumbel + argmax + softmax/logp + state update (verified math) ----
    float masked = -INFINITY, z = -INFINITY; int zi = 256;
    if (tid2 < NN) {
      masked = (av[sg][tid2] != 0.0f) ? ms[sg][tid2] : -1e9f;
      uint32_t o0, o1; tf2x32(sk0, sk1, 0u, (uint32_t)((b0 + sg) * NN + tid2), o0, o1);
      uint32_t bits = o0 ^ o1;
      float f = __uint_as_float((bits >> 9) | 0x3f800000u) - 1.0f;
      const float TINY = 1.1754943508222875e-38f;
      f = f * (1.0f - TINY) + TINY;
      float gg = -logf(-logf(fmaxf(f, TINY)));
      z = gg + masked;
      zi = tid2;
    }
    {
      float rv = z; int ri = zi; float rm = masked;
#pragma unroll
      for (int d = 32; d > 0; d >>= 1) {
        float ov = __shfl_down(rv, d); int oi = __shfl_down(ri, d);
        float om = __shfl_down(rm, d);
        if (ov > rv || (ov == rv && oi < ri)) { rv = ov; ri = oi; }
        rm = fmaxf(rm, om);
      }
      if (l == 0) { wredv[sg][wg] = rv; wredi[sg][wg] = ri; wmaxs[sg][wg] = rm; }
    }
    __syncthreads();
    if (tid2 == 0) {
      float bv = wredv[sg][0]; int bi = wredi[sg][0]; float bm = wmaxs[sg][0];
#pragma unroll
      for (int k = 1; k < 4; ++k) {
        float ov = wredv[sg][k]; int oi = wredi[sg][k];
        if (ov > bv || (ov == bv && oi < bi)) { bv = ov; bi = oi; }
        bm = fmaxf(bm, wmaxs[sg][k]);
      }
      schosen[sg] = bi; smaxs[sg] = bm;
    }
    __syncthreads();
    const int chosen = schosen[sg]; const float maxm = smaxs[sg];
    if (tid2 < 128) {
      float dv = di[((size_t)((b0 + sg) * 201 + chosen)) * 128 + tid2];
      xcb[sg][0][tid2] = dv; xcb[sg][1][tid2] = dv;
    }
    if (tid2 == chosen) av[sg][tid2] = 0.0f;
    float ev = (tid2 < NN) ? expf(masked - maxm) : 0.0f;
    {
      float sv = ev;
#pragma unroll
      for (int d = 32; d > 0; d >>= 1) sv += __shfl_down(sv, d);
      if (l == 0) wsums[sg][wg] = sv;
    }
    __syncthreads();
    if (tid2 == 0)
      ssums[sg] = (wsums[sg][0] + wsums[sg][1]) + (wsums[sg][2] + wsums[sg][3]);
    __syncthreads();
    if (tid2 < NN)
      out_logp[((size_t)((b0 + sg) * TT + t)) * NN + tid2] =
          logf(ev / ssums[sg] + 1e-9f);
    if (tid2 == 0) out_idx[(b0 + sg) * TT + t] = (float)chosen;
    __syncthreads();
  }
}

extern "C" void kernel_launch(void* const* d_in, const int* in_sizes, int n_in,
                              void* d_out, int out_size, void* d_ws, size_t ws_size,
                              hipStream_t stream) {
  const float* enc  = (const float*)d_in[0];
  const float* pt   = (const float*)d_in[1];
  const float* nm   = (const float*)d_in[2];
  const float* w1ih = (const float*)d_in[3];
  const float* whh1 = (const float*)d_in[4];
  const float* b1   = (const float*)d_in[5];
  const float* mw   = (const float*)d_in[6];
  const float* mb   = (const float*)d_in[7];
  const float* fcW  = (const float*)d_in[8];
  const float* fcb  = (const float*)d_in[9];
  const float* d0h  = (const float*)d_in[10];
  const float* w2ih = (const float*)d_in[11];
  const float* w2hh = (const float*)d_in[12];
  const float* b2   = (const float*)d_in[13];
  const float* aw1  = (const float*)d_in[14];
  const float* ab1  = (const float*)d_in[15];
  const float* aw2  = (const float*)d_in[16];
  const float* ab2  = (const float*)d_in[17];
  const float* av   = (const float*)d_in[18];

  float* out      = (float*)d_out;
  float* out_idx  = out;                              // [512,200]
  float* out_logp = out + 102400;                     // [512,200,200]
  float* out_enc  = out + 102400 + 20480000;          // [512,200,256] (pre scratch)
  float* pre      = out_enc;

  float* ws     = (float*)d_ws;
  float* W1T    = ws;                       // 65536
  float* fcWT   = ws + 65536;               // 20480   [160][128]
  float* attW2T = ws + 86016;               // 65536   [256][256] k-major
  float* Wc2    = ws + 151552;              // 98304   [384][256] k-major
  float* di     = ws + 249856;              // 13172736 [512*201][128]

  k_transpose<<<(65536 + 255) / 256, 256, 0, stream>>>(aw1, W1T,    256, 256);
  k_transpose<<<(20480 + 255) / 256, 256, 0, stream>>>(fcW, fcWT,   128, 160);
  k_transpose<<<(65536 + 255) / 256, 256, 0, stream>>>(aw2, attW2T, 256, 256);
  k_pack2<<<384, 256, 0, stream>>>(w2ih, w2hh, Wc2);

  dim3 gpre(NN / NR, BB);
  k_pre<<<gpre, 256, 0, stream>>>(enc, W1T, ab1, pre);

  k_di<<<BB * 201, 512, 0, stream>>>(pt, nm, w1ih, b1, whh1, mw, mb, fcWT, fcb, di);

  k_full<<<BB / 2, 512, 0, stream>>>(pre, av, Wc2, b2, attW2T, ab2, d0h, di,
                                     out_idx, out_logp);

  k_copy4<<<(6553600 + 255) / 256, 256, 0, stream>>>((const f4v*)enc,
                                                     (f4v*)out_enc, 6553600);
}

// Round 18
// 9140.602 us; speedup vs baseline: 2.0579x; 2.0579x over previous
//
#include <hip/hip_runtime.h>
#include <hip/hip_bf16.h>
#include <stdint.h>

#define BB 512
#define NN 200
#define TT 200
#define MM 20
#define H1N 128
#define MEN 32
#define DIN 128
#define H2N 256
#define JDN 256
#define AHN 256

#define PRE_REG 20   // pre rows per wave held in registers (4 waves/batch -> 80 rows)
#define PRE_LDSB 32  // pre rows per batch held in LDS
// per batch: rows [0,80) regs, [80,112) LDS, [112,200) streamed from L3

typedef float f4v __attribute__((ext_vector_type(4)));

// ---------------- threefry2x32 (JAX-exact) ----------------
__device__ __forceinline__ void tf2x32(uint32_t k0, uint32_t k1,
                                       uint32_t x0, uint32_t x1,
                                       uint32_t& o0, uint32_t& o1) {
  uint32_t ks2 = k0 ^ k1 ^ 0x1BD11BDAu;
  x0 += k0; x1 += k1;
#define TF_RND(R) { x0 += x1; x1 = (x1 << (R)) | (x1 >> (32 - (R))); x1 ^= x0; }
  TF_RND(13) TF_RND(15) TF_RND(26) TF_RND(6)   x0 += k1;  x1 += ks2 + 1u;
  TF_RND(17) TF_RND(29) TF_RND(16) TF_RND(24)  x0 += ks2; x1 += k0 + 2u;
  TF_RND(13) TF_RND(15) TF_RND(26) TF_RND(6)   x0 += k0;  x1 += k1 + 3u;
  TF_RND(17) TF_RND(29) TF_RND(16) TF_RND(24)  x0 += k1;  x1 += ks2 + 4u;
  TF_RND(13) TF_RND(15) TF_RND(26) TF_RND(6)   x0 += ks2; x1 += k0 + 5u;
#undef TF_RND
  o0 = x0; o1 = x1;
}

// fast tanh for the scores phase (verified R11-R15, absmax <=0.0625):
// tanh(x) = 1 - 2/(exp(2x)+1) via v_exp_f32 + v_rcp_f32 + 1 Newton step.
__device__ __forceinline__ float ftanh(float x) {
  float e = __builtin_amdgcn_exp2f(x * 2.8853900817779268f);  // exp(2x)
  float d = e + 1.0f;
  float r = __builtin_amdgcn_rcpf(d);
  r = r * (2.0f - d * r);
  return 1.0f - 2.0f * r;
}

// ---------------- small utility kernels ----------------
__global__ void k_transpose(const float* __restrict__ in, float* __restrict__ out,
                            int R, int C) {
  int idx = blockIdx.x * 256 + threadIdx.x;
  if (idx < R * C) { int r = idx / C, c = idx - r * C; out[c * R + r] = in[idx]; }
}

// Wc2[k*256+o]: k<128 -> w2ih[o*128+k]; k>=128 -> w2hh[o*256+(k-128)]
__global__ void k_pack2(const float* __restrict__ w2ih, const float* __restrict__ w2hh,
                        float* __restrict__ Wc2) {
  int idx = blockIdx.x * 256 + threadIdx.x;     // 384*256
  int o = idx & 255, k = idx >> 8;
  Wc2[idx] = (k < 128) ? w2ih[o * 128 + k] : w2hh[o * 256 + (k - 128)];
}

__global__ void k_copy4(const f4v* __restrict__ in, f4v* __restrict__ out, int n4) {
  int i = blockIdx.x * 256 + threadIdx.x;
  if (i < n4) out[i] = in[i];
}

// ---------------- pre_att = enc @ W1^T + b1 ----------------
#define NR 20
__global__ __launch_bounds__(256) void k_pre(const float* __restrict__ enc,
                                             const float* __restrict__ W1T,
                                             const float* __restrict__ ab1,
                                             float* __restrict__ pre) {
  const int b = blockIdx.y, n0 = blockIdx.x * NR, tid = threadIdx.x;
  __shared__ __align__(16) float es[NR * JDN];
  for (int r = 0; r < NR; ++r)
    es[r * JDN + tid] = enc[((size_t)(b * NN + n0 + r)) * JDN + tid];
  __syncthreads();
  float acc[NR];
#pragma unroll
  for (int r = 0; r < NR; ++r) acc[r] = 0.0f;
  const f4v* es4 = (const f4v*)es;
  for (int k0 = 0; k0 < JDN; k0 += 4) {
    float w0 = W1T[(k0 + 0) * AHN + tid];
    float w1 = W1T[(k0 + 1) * AHN + tid];
    float w2 = W1T[(k0 + 2) * AHN + tid];
    float w3 = W1T[(k0 + 3) * AHN + tid];
#pragma unroll
    for (int r = 0; r < NR; ++r) {
      f4v e = es4[r * 64 + (k0 >> 2)];
      acc[r] += e.x * w0 + e.y * w1 + e.z * w2 + e.w * w3;
    }
  }
  float bb = ab1[tid];
  for (int r = 0; r < NR; ++r)
    pre[((size_t)(b * NN + n0 + r)) * AHN + tid] = acc[r] + bb;
}

// ---------------- di table: step1 RNN + fc for all (b, n) ----------------
// chain = b*201 + n; n==200 is the zero-P initial state. (verified round 4)
__global__ __launch_bounds__(512) void k_di(
    const float* __restrict__ pt, const float* __restrict__ nm,
    const float* __restrict__ w1ih, const float* __restrict__ b1,
    const float* __restrict__ whh,
    const float* __restrict__ mw, const float* __restrict__ mb,
    const float* __restrict__ fcWT, const float* __restrict__ fcb,
    float* __restrict__ diOut) {
  const int chain = blockIdx.x;
  const int b = chain / 201, n = chain - b * 201;
  const int tid = threadIdx.x;
  const int w = tid >> 6, l = tid & 63;

  __shared__ __align__(16) float hm[320];
  __shared__ float Ps[40];
  __shared__ float partial[512];

  const int j = (w << 4) + (l & 15);
  const int ks = l >> 4;
  float wr[32];
  {
    const float* wp = whh + j * H1N + ks * 32;
#pragma unroll
    for (int i = 0; i < 32; i += 4) {
      f4v t4 = *(const f4v*)(wp + i);
      wr[i] = t4.x; wr[i + 1] = t4.y; wr[i + 2] = t4.z; wr[i + 3] = t4.w;
    }
  }
  const float w1a = w1ih[2 * j], w1b = w1ih[2 * j + 1], b1j = b1[j];
  const float fcb_r = (tid < 128) ? fcb[tid] : 0.0f;

  if (tid < 32)  hm[288 + tid] = nm[b] * mw[tid] + mb[tid];
  if (tid >= 64 && tid < 192) {
    int p = tid - 64;
    hm[(p >> 5) * 36 + (p & 31)] = 0.0f;
  }
  if (tid < 40)
    Ps[tid] = (n < NN) ? pt[((size_t)(b * NN + n)) * (MM * 2) + tid] : 0.0f;
  __syncthreads();

  for (int m = 0; m < MM; ++m) {
    float x0 = Ps[2 * m], x1 = Ps[2 * m + 1];
    float acc = 0.0f;
    const f4v* hm4 = (const f4v*)(hm + (m & 1) * 144 + ks * 36);
#pragma unroll
    for (int i = 0; i < 8; ++i) {
      f4v hv = hm4[i];
      acc += wr[4 * i] * hv.x;     acc += wr[4 * i + 1] * hv.y;
      acc += wr[4 * i + 2] * hv.z; acc += wr[4 * i + 3] * hv.w;
    }
    acc += __shfl_xor(acc, 16);
    acc += __shfl_xor(acc, 32);
    if (ks == 0) {
      float hv = tanhf(acc + x0 * w1a + x1 * w1b + b1j);
      hm[(1 - (m & 1)) * 144 + (j >> 5) * 36 + (j & 31)] = hv;
    }
    __syncthreads();
  }

  {
    const int ksf = tid >> 7, o = tid & 127, k0 = ksf * 40;
    float a0=0,a1=0,a2=0,a3=0,a4=0,a5=0,a6=0,a7=0;
#pragma unroll
    for (int i0 = 0; i0 < 40; i0 += 8) {
#pragma unroll
      for (int q8 = 0; q8 < 8; ++q8) {
        int k = k0 + i0 + q8;
        float hv = (k < 128) ? hm[(k >> 5) * 36 + (k & 31)] : hm[288 + (k - 128)];
        float wv = fcWT[k * 128 + o];
        if (q8 == 0) a0 += hv * wv; else if (q8 == 1) a1 += hv * wv;
        else if (q8 == 2) a2 += hv * wv; else if (q8 == 3) a3 += hv * wv;
        else if (q8 == 4) a4 += hv * wv; else if (q8 == 5) a5 += hv * wv;
        else if (q8 == 6) a6 += hv * wv; else a7 += hv * wv;
      }
    }
    partial[tid] = ((a0 + a1) + (a2 + a3)) + ((a4 + a5) + (a6 + a7));
    __syncthreads();
    if (tid < 128)
      diOut[(size_t)chain * 128 + tid] =
          partial[tid] + partial[128 + tid] + partial[256 + tid] +
          partial[384 + tid] + fcb_r;
  }
}

// ---------------- k_full: R8 structure + ftanh in scores (= round-15 best) ----------------
// 256 blocks x 512 threads (1 block/CU, grid-limited). Block = 2 batches.
// Per step: 20-tile dbuf pipeline (12x Wc2 + 8x attW2T, 32KB tiles) staged
// global->reg->LDS; both batch halves compute matvecs from LDS (b32 reads,
// VGPR-cheap). pre pinned: 80 rows regs + 32 rows LDS + 88 streamed.
__global__ __launch_bounds__(512) void k_full(
    const float* __restrict__ pre, const float* __restrict__ attv,
    const float* __restrict__ Wc2, const float* __restrict__ b2,
    const float* __restrict__ attW2T, const float* __restrict__ ab2,
    const float* __restrict__ d0h, const float* __restrict__ di,
    float* __restrict__ out_idx, float* __restrict__ out_logp) {
  const int b0 = blockIdx.x * 2, tid = threadIdx.x;
  const int w = tid >> 6, l = tid & 63;
  const int o = tid & 255, g = tid >> 8;        // GEMM role: batch-half g, output o
  const int sg = w >> 2, wg = w & 3;            // sampling role: waves 0-3 batch0, 4-7 batch1
  const int tid2 = wg * 64 + l;                 // 0..255 within batch group

  __shared__ __align__(16) float wlds[2][8192];        // 2 x 32KB weight tiles
  __shared__ __align__(16) float pre_lds[2][PRE_LDSB * 256];
  __shared__ __align__(16) float xcb[2][2][384];       // [batch][buf][di(128);h2(256)]
  __shared__ __align__(16) float qs_g[2][256];
  __shared__ float ms[2][200];
  __shared__ float av[2][200];
  __shared__ float wredv[2][4]; __shared__ int wredi[2][4];
  __shared__ float wmaxs[2][4]; __shared__ float wsums[2][4];
  __shared__ int schosen[2]; __shared__ float smaxs[2], ssums[2];

  // ---- pin pre rows 0..79 (regs, per batch via sg) ----
  float preg[PRE_REG][4];
  const float* pb = pre + (size_t)(b0 + sg) * NN * AHN;
#pragma unroll
  for (int r = 0; r < PRE_REG; ++r) {
    const float* pr = pb + (size_t)(wg * PRE_REG + r) * AHN + l;
#pragma unroll
    for (int jj = 0; jj < 4; ++jj) preg[r][jj] = pr[jj * 64];
  }
  // ---- pin pre rows 80..111 in LDS (both batches) ----
  for (int i = tid; i < 2 * PRE_LDSB * 64; i += 512) {
    int bb = i >> 11;                 // 2048 f4v per batch
    int rem = i & 2047;
    ((f4v*)pre_lds[bb])[rem] =
        ((const f4v*)(pre + ((size_t)((b0 + bb) * NN + 80)) * AHN))[rem];
  }

  const float b2r  = b2[o];
  const float ab2r = ab2[o];
  const float v0 = attv[l], v1 = attv[l + 64], v2 = attv[l + 128], v3 = attv[l + 192];

  xcb[g][0][128 + o] = d0h[o];
  if (tid < 256) {
    int gg = tid >> 7, k = tid & 127;
    float dv = di[((size_t)((b0 + gg) * 201 + 200)) * 128 + k];
    xcb[gg][0][k] = dv; xcb[gg][1][k] = dv;
  }
  if (tid < 400) { int gg = tid / 200, n = tid - gg * 200; av[gg][n] = 1.0f; }

  // ---- prologue: stage tile 0 (first 32KB of Wc2) ----
  {
    const f4v* src = (const f4v*)Wc2;
    f4v* dst = (f4v*)wlds[0];
    dst[tid] = src[tid]; dst[512 + tid] = src[512 + tid];
    dst[1024 + tid] = src[1024 + tid]; dst[1536 + tid] = src[1536 + tid];
  }
  __syncthreads();

  for (int t = 0; t < TT; ++t) {
    const int XB = t & 1, NB = XB ^ 1;
    uint32_t sk0, sk1; tf2x32(0u, 42u, 0u, (uint32_t)t, sk0, sk1);

    float acc1 = 0.0f, acc2 = 0.0f;
    for (int tile = 0; tile < 20; ++tile) {
      const int cur = tile & 1;
      // stage next tile (wraps to next step's tile 0 at tile==19)
      int nt = tile + 1; if (nt == 20) nt = 0;
      const f4v* src = (const f4v*)((nt < 12) ? (Wc2 + nt * 8192)
                                              : (attW2T + (nt - 12) * 8192));
      f4v s0 = src[tid], s1 = src[512 + tid], s2 = src[1024 + tid],
          s3 = src[1536 + tid];

      if (tile == 12) {           // h2n handoff: acc1 is final after tile 11
        xcb[g][NB][128 + o] = tanhf(acc1 + b2r);
        __syncthreads();
      }

      const float* xsrc = (tile < 12) ? &xcb[g][XB][tile * 32]
                                      : &xcb[g][NB][128 + (tile - 12) * 32];
      f4v xr[8];
#pragma unroll
      for (int i = 0; i < 8; ++i) xr[i] = ((const f4v*)xsrc)[i];

      const float* wl = wlds[cur];
      float a = 0.0f;
#pragma unroll
      for (int kk = 0; kk < 32; ++kk)
        a += xr[kk >> 2][kk & 3] * wl[kk * 256 + o];
      if (tile < 12) acc1 += a; else acc2 += a;

      f4v* wd = (f4v*)wlds[cur ^ 1];
      wd[tid] = s0; wd[512 + tid] = s1; wd[1024 + tid] = s2; wd[1536 + tid] = s3;
      __syncthreads();
    }

    qs_g[g][o] = acc2 + ab2r;
    __syncthreads();

    // ---- scores: wave wg of group sg covers 50 rows (20 reg + 8 LDS + 22 stream) ----
    {
      const float q0 = qs_g[sg][l],       q1 = qs_g[sg][l + 64];
      const float q2 = qs_g[sg][l + 128], q3 = qs_g[sg][l + 192];
#pragma unroll
      for (int r = 0; r < PRE_REG; ++r) {
        float s0 = ftanh(preg[r][0] + q0) * v0;
        float s1 = ftanh(preg[r][1] + q1) * v1;
        float s2 = ftanh(preg[r][2] + q2) * v2;
        float s3 = ftanh(preg[r][3] + q3) * v3;
        float s = (s0 + s1) + (s2 + s3);
#pragma unroll
        for (int d = 32; d > 0; d >>= 1) s += __shfl_down(s, d);
        if (l == 0) ms[sg][wg * PRE_REG + r] = s;
      }
#pragma unroll
      for (int i = 0; i < 8; ++i) {
        const float* pr = pre_lds[sg] + (wg * 8 + i) * 256;
        float s0 = ftanh(pr[l]       + q0) * v0;
        float s1 = ftanh(pr[l + 64]  + q1) * v1;
        float s2 = ftanh(pr[l + 128] + q2) * v2;
        float s3 = ftanh(pr[l + 192] + q3) * v3;
        float s = (s0 + s1) + (s2 + s3);
#pragma unroll
        for (int d = 32; d > 0; d >>= 1) s += __shfl_down(s, d);
        if (l == 0) ms[sg][80 + wg * 8 + i] = s;
      }
      // streamed rows 112..199, depth-1 prefetch
      const float* prow = pb + (size_t)(112 + wg * 22) * AHN;
      float c0 = prow[l], c1 = prow[l + 64], c2 = prow[l + 128], c3 = prow[l + 192];
      for (int i = 0; i < 22; ++i) {
        const float* nr = prow + AHN;
        float n0 = 0, n1 = 0, n2 = 0, n3 = 0;
        if (i < 21) { n0 = nr[l]; n1 = nr[l + 64]; n2 = nr[l + 128]; n3 = nr[l + 192]; }
        float s0 = ftanh(c0 + q0) * v0;
        float s1 = ftanh(c1 + q1) * v1;
        float s2 = ftanh(c2 + q2) * v2;
        float s3 = ftanh(c3 + q3) * v3;
        float s = (s0 + s1) + (s2 + s3);
#pragma unroll
        for (int d = 32; d > 0; d >>= 1) s += __shfl_down(s, d);
        if (l == 0) ms[sg][112 + wg * 22 + i] = s;
        c0 = n0; c1 = n1; c2 = n2; c3 = n3; prow = nr;
      }
    }
    __syncthreads();

    // ---- gumbel + argmax + softmax/logp + state update (verified math) ----
    float masked = -INFINITY, z = -INFINITY; int zi = 256;
    if (tid2 < NN) {
      masked = (av[sg][tid2] != 0.0f) ? ms[sg][tid2] : -1e9f;
      uint32_t o0, o1; tf2x32(sk0, sk1, 0u, (uint32_t)((b0 + sg) * NN + tid2), o0, o1);
      uint32_t bits = o0 ^ o1;
      float f = __uint_as_float((bits >> 9) | 0x3f800000u) - 1.0f;
      const float TINY = 1.1754943508222875e-38f;
      f = f * (1.0f - TINY) + TINY;
      float gg = -logf(-logf(fmaxf(f, TINY)));
      z = gg + masked;
      zi = tid2;
    }
    {
      float rv = z; int ri = zi; float rm = masked;
#pragma unroll
      for (int d = 32; d > 0; d >>= 1) {
        float ov = __shfl_down(rv, d); int oi = __shfl_down(ri, d);
        float om = __shfl_down(rm, d);
        if (ov > rv || (ov == rv && oi < ri)) { rv = ov; ri = oi; }
        rm = fmaxf(rm, om);
      }
      if (l == 0) { wredv[sg][wg] = rv; wredi[sg][wg] = ri; wmaxs[sg][wg] = rm; }
    }
    __syncthreads();
    if (tid2 == 0) {
      float bv = wredv[sg][0]; int bi = wredi[sg][0]; float bm = wmaxs[sg][0];
#pragma unroll
      for (int k = 1; k < 4; ++k) {
        float ov = wredv[sg][k]; int oi = wredi[sg][k];
        if (ov > bv || (ov == bv && oi < bi)) { bv = ov; bi = oi; }
        bm = fmaxf(bm, wmaxs[sg][k]);
      }
      schosen[sg] = bi; smaxs[sg] = bm;
    }
    __syncthreads();
    const int chosen = schosen[sg]; const float maxm = smaxs[sg];
    if (tid2 < 128) {
      float dv = di[((size_t)((b0 + sg) * 201 + chosen)) * 128 + tid2];
      xcb[sg][0][tid2] = dv; xcb[sg][1][tid2] = dv;
    }
    if (tid2 == chosen) av[sg][tid2] = 0.0f;
    float ev = (tid2 < NN) ? expf(masked - maxm) : 0.0f;
    {
      float sv = ev;
#pragma unroll
      for (int d = 32; d > 0; d >>= 1) sv += __shfl_down(sv, d);
      if (l == 0) wsums[sg][wg] = sv;
    }
    __syncthreads();
    if (tid2 == 0)
      ssums[sg] = (wsums[sg][0] + wsums[sg][1]) + (wsums[sg][2] + wsums[sg][3]);
    __syncthreads();
    if (tid2 < NN)
      out_logp[((size_t)((b0 + sg) * TT + t)) * NN + tid2] =
          logf(ev / ssums[sg] + 1e-9f);
    if (tid2 == 0) out_idx[(b0 + sg) * TT + t] = (float)chosen;
    __syncthreads();
  }
}

extern "C" void kernel_launch(void* const* d_in, const int* in_sizes, int n_in,
                              void* d_out, int out_size, void* d_ws, size_t ws_size,
                              hipStream_t stream) {
  const float* enc  = (const float*)d_in[0];
  const float* pt   = (const float*)d_in[1];
  const float* nm   = (const float*)d_in[2];
  const float* w1ih = (const float*)d_in[3];
  const float* whh1 = (const float*)d_in[4];
  const float* b1   = (const float*)d_in[5];
  const float* mw   = (const float*)d_in[6];
  const float* mb   = (const float*)d_in[7];
  const float* fcW  = (const float*)d_in[8];
  const float* fcb  = (const float*)d_in[9];
  const float* d0h  = (const float*)d_in[10];
  const float* w2ih = (const float*)d_in[11];
  const float* w2hh = (const float*)d_in[12];
  const float* b2   = (const float*)d_in[13];
  const float* aw1  = (const float*)d_in[14];
  const float* ab1  = (const float*)d_in[15];
  const float* aw2  = (const float*)d_in[16];
  const float* ab2  = (const float*)d_in[17];
  const float* av   = (const float*)d_in[18];

  float* out      = (float*)d_out;
  float* out_idx  = out;                              // [512,200]
  float* out_logp = out + 102400;                     // [512,200,200]
  float* out_enc  = out + 102400 + 20480000;          // [512,200,256] (pre scratch)
  float* pre      = out_enc;

  float* ws     = (float*)d_ws;
  float* W1T    = ws;                       // 65536
  float* fcWT   = ws + 65536;               // 20480   [160][128]
  float* attW2T = ws + 86016;               // 65536   [256][256] k-major
  float* Wc2    = ws + 151552;              // 98304   [384][256] k-major
  float* di     = ws + 249856;              // 13172736 [512*201][128]

  k_transpose<<<(65536 + 255) / 256, 256, 0, stream>>>(aw1, W1T,    256, 256);
  k_transpose<<<(20480 + 255) / 256, 256, 0, stream>>>(fcW, fcWT,   128, 160);
  k_transpose<<<(65536 + 255) / 256, 256, 0, stream>>>(aw2, attW2T, 256, 256);
  k_pack2<<<384, 256, 0, stream>>>(w2ih, w2hh, Wc2);

  dim3 gpre(NN / NR, BB);
  k_pre<<<gpre, 256, 0, stream>>>(enc, W1T, ab1, pre);

  k_di<<<BB * 201, 512, 0, stream>>>(pt, nm, w1ih, b1, whh1, mw, mb, fcWT, fcb, di);

  k_full<<<BB / 2, 512, 0, stream>>>(pre, av, Wc2, b2, attW2T, ab2, d0h, di,
                                     out_idx, out_logp);

  k_copy4<<<(6553600 + 255) / 256, 256, 0, stream>>>((const f4v*)enc,
                                                     (f4v*)out_enc, 6553600);
}